// Round 27
// baseline (161.074 us; speedup 1.0000x reference)
//
#include <hip/hip_runtime.h>
#include <hip/hip_bf16.h>
#include <cstdint>

// ---------------------------------------------------------------------------
// Binarized CNN. Verified numerics (R5-R26 passed bit-exact):
//  - binarize(x) == sign(x) exactly; layers 2-4 are exact small-int math in
//    any order -> any packing / instruction choice is safe.
//  - conv1: each accumulator chain MUST sum in (ky,kx,ic)-ascending order
//    (Eigen/XLA-CPU im2col). Chains independent; fma == mul+add (w in +-1/0).
//    DO NOT reorder WITHIN a chain. Pad value 1.0.
//  - k2/kconv34: tap-packed MFMA K-axis (R25, verified).
//  - R27: k1 OC-SPLIT across thread-groups: group g = tid>>7 computes
//    op-pairs {2g,2g+1} only (216 pkfma/thread, was 432) and writes its
//    own plane dword. 2x waves per output row -> latency overlap. Window
//    loads duplicated across groups (same addrs, same block -> L1).
// ---------------------------------------------------------------------------

typedef __attribute__((ext_vector_type(2)))  float f32x2;
typedef __attribute__((ext_vector_type(4)))  int int4v;
typedef __attribute__((ext_vector_type(16))) int int16v;

#define WOFF_W2M 0          // int[3*64*4]  (L2 quad-tap table)
#define WOFF_W3M 10240      // int[5*64*4]  (L3 pair-tap table)
#define WOFF_W4M 20480      // int[9*64*4]  (L4 table, K=32 full)
#define WOFF_W1D 30720      // f32x2[4*32]
#define WEIGHTS_BYTES 32768

#define A1_PB (2*256*256*4)     // bytes per batch (packed u32, 4 ch/dword)
#define A2_PB (254*254*4*4)     // bytes per batch (pixel-major, 4 ocg dwords)

__device__ __forceinline__ int fsign(float w) {
    return (w > 0.f) ? 1 : ((w < 0.f) ? -1 : 0);
}

// acc.lo += w.lo * v.lo ; acc.hi += w.hi * v.lo   (broadcast LOW of src1)
__device__ __forceinline__ void pkfma_lo(f32x2& acc, f32x2 w, f32x2 v) {
    asm("v_pk_fma_f32 %0, %1, %2, %0 op_sel:[0,0,0] op_sel_hi:[1,0,1]"
        : "+v"(acc) : "s"(w), "v"(v));
}
// acc.lo += w.lo * v.hi ; acc.hi += w.hi * v.hi   (broadcast HIGH of src1)
__device__ __forceinline__ void pkfma_hi(f32x2& acc, f32x2 w, f32x2 v) {
    asm("v_pk_fma_f32 %0, %1, %2, %0 op_sel:[0,1,0] op_sel_hi:[1,1,1]"
        : "+v"(acc) : "s"(w), "v"(v));
}

// ---- weight prep: 3 blocks (one per table group) -------------------------
__global__ __launch_bounds__(256) void kprep(const float* __restrict__ w1,
                                             const float* __restrict__ w2,
                                             const float* __restrict__ w3,
                                             const float* __restrict__ w4,
                                             int* __restrict__ w2m,
                                             int* __restrict__ w3m,
                                             int* __restrict__ w4m,
                                             f32x2* __restrict__ w1d) {
    int tid = threadIdx.x;
    int b = blockIdx.x;
    if (b == 0) {
        // L2 quad-tap table (R25-verified)
        for (int idx = tid; idx < 3 * 64; idx += 256) {
            int q = idx / 64, l = idx % 64;
            int oc = l & 31, hl = l >> 5;
            int wd[4] = {0, 0, 0, 0};
            for (int u = 0; u < 2; ++u) {
                int tap = 4 * q + 2 * hl + u;
                if (tap > 8) continue;
                for (int i = 0; i < 8; ++i) {
                    int s = (oc < 16) ? fsign(w2[(oc * 8 + i) * 9 + tap]) : 0;
                    int j = 8 * u + i;
                    wd[j >> 2] |= (s & 0xff) << (8 * (j & 3));
                }
            }
            w2m[idx * 4 + 0] = wd[0]; w2m[idx * 4 + 1] = wd[1];
            w2m[idx * 4 + 2] = wd[2]; w2m[idx * 4 + 3] = wd[3];
        }
    } else if (b == 1) {
        // L3 pair-tap table (R25-verified)
        for (int idx = tid; idx < 5 * 64; idx += 256) {
            int p = idx / 64, l = idx % 64;
            int oc = l & 31, hl = l >> 5;
            int wd[4] = {0, 0, 0, 0};
            int tap = (p < 4) ? (2 * p + hl) : ((hl == 0) ? 8 : -1);
            if (tap >= 0) {
                for (int j = 0; j < 16; ++j) {
                    int s = fsign(w3[(oc * 16 + j) * 9 + tap]);
                    wd[j >> 2] |= (s & 0xff) << (8 * (j & 3));
                }
            }
            w3m[idx * 4 + 0] = wd[0]; w3m[idx * 4 + 1] = wd[1];
            w3m[idx * 4 + 2] = wd[2]; w3m[idx * 4 + 3] = wd[3];
        }
    } else {
        // L4 table: K=32 all real, only oc 0,1 nonzero (R22-verified)
        for (int idx = tid; idx < 576; idx += 256) {
            int t = idx / 64, l = idx % 64;
            int oc = l & 31, icb = (l >> 5) * 16;
            int wd[4] = {0, 0, 0, 0};
            for (int j = 0; j < 16; ++j) {
                int ic = icb + j;
                int s = (oc < 2) ? fsign(w4[(oc * 32 + ic) * 9 + t]) : 0;
                wd[j >> 2] |= (s & 0xff) << (8 * (j & 3));
            }
            w4m[idx * 4 + 0] = wd[0]; w4m[idx * 4 + 1] = wd[1];
            w4m[idx * 4 + 2] = wd[2]; w4m[idx * 4 + 3] = wd[3];
        }
        for (int i = tid; i < 128; i += 256) {
            int op = i / 32, t = i % 32;
            f32x2 pr = {0.f, 0.f};
            if (t < 27) {
                float wa = w1[(2 * op) * 27 + t];
                float wbv = w1[(2 * op + 1) * 27 + t];
                pr[0] = (wa > 0.f) ? 1.f : ((wa < 0.f) ? -1.f : 0.f);
                pr[1] = (wbv > 0.f) ? 1.f : ((wbv < 0.f) ? -1.f : 0.f);
            }
            w1d[i] = pr;
        }
    }
}

// ---- layer 1: pad(1)+conv(3->8)+hardtanh+maxpool2+sign, packed out -------
// R27: oc-split. Group g = tid>>7 computes op-pairs {2g, 2g+1}; per-chain
// summation order unchanged (strict (ky,kx,ic)-ascending) -> bit-exact.
__global__ __launch_bounds__(256, 4) void k1(const float* __restrict__ x,
                                             const f32x2* __restrict__ w1d,
                                             uint32_t* __restrict__ a1, int n0) {
    int tx = threadIdx.x & 127;              // 0..127: 2-cell column pair
    int g  = threadIdx.x >> 7;               // 0..1: op-group (plane)
    int oy = blockIdx.y;                     // 0..255
    int ln = blockIdx.z;
    const float* xn = x + (size_t)(n0 + ln) * 3 * 512 * 512;

    int iy0 = 2 * oy - 1;
    int xb  = 4 * tx;        // window cols xb-1 .. xb+4

    f32x2 P[3][4][3];        // [ic][r][pair]

    if (oy > 0 && oy < 255 && tx > 0 && tx < 127) {
#pragma unroll
        for (int ic = 0; ic < 3; ++ic) {
            const float* xc = xn + (size_t)ic * 512 * 512;
#pragma unroll
            for (int r = 0; r < 4; ++r) {
                const float* rp = xc + (size_t)(iy0 + r) * 512 + xb;
                float  lft = rp[-1];
                float4 m   = *(const float4*)rp;    // cols xb..xb+3, 16B aligned
                float  rgt = rp[4];
                P[ic][r][0] = (f32x2){lft, m.x};
                P[ic][r][1] = (f32x2){m.y, m.z};
                P[ic][r][2] = (f32x2){m.w, rgt};
            }
        }
    } else {
        for (int ic = 0; ic < 3; ++ic) {
            const float* xc = xn + (size_t)ic * 512 * 512;
#pragma unroll
            for (int r = 0; r < 4; ++r) {
                int iy = iy0 + r;
                bool yok = ((unsigned)iy < 512u);
                float t[6];
#pragma unroll
                for (int c = 0; c < 6; ++c) {
                    int ix = xb - 1 + c;
                    t[c] = (yok && ((unsigned)ix < 512u))
                               ? xc[(size_t)iy * 512 + ix] : 1.0f;
                }
                P[ic][r][0] = (f32x2){t[0], t[1]};
                P[ic][r][1] = (f32x2){t[2], t[3]};
                P[ic][r][2] = (f32x2){t[4], t[5]};
            }
        }
    }

#define PKTAP(ACC, ROW, COL)                                         \
    do {                                                             \
        if (((COL) & 1) == 0) pkfma_lo(ACC, ww, P[ic][ROW][(COL) >> 1]); \
        else                  pkfma_hi(ACC, ww, P[ic][ROW][(COL) >> 1]); \
    } while (0)

    uint32_t dwA = 0, dwB = 0;   // this group's plane dword for cells A, B
#pragma unroll 1
    for (int lop = 0; lop < 2; ++lop) {
        int op = 2 * g + lop;
        const f32x2* wb = w1d + op * 32;
        f32x2 wop[27];
#pragma unroll
        for (int t = 0; t < 27; ++t) wop[t] = wb[t];

        f32x2 aA00 = {0.f, 0.f}, aA01 = {0.f, 0.f};
        f32x2 aA10 = {0.f, 0.f}, aA11 = {0.f, 0.f};
        f32x2 aB00 = {0.f, 0.f}, aB01 = {0.f, 0.f};
        f32x2 aB10 = {0.f, 0.f}, aB11 = {0.f, 0.f};
#pragma unroll
        for (int ky = 0; ky < 3; ++ky) {
#pragma unroll
            for (int kx = 0; kx < 3; ++kx) {
#pragma unroll
                for (int ic = 0; ic < 3; ++ic) {
                    f32x2 ww = wop[ic * 9 + ky * 3 + kx];
                    PKTAP(aA00, ky + 0, kx + 0);
                    PKTAP(aA01, ky + 0, kx + 1);
                    PKTAP(aA10, ky + 1, kx + 0);
                    PKTAP(aA11, ky + 1, kx + 1);
                    PKTAP(aB00, ky + 0, kx + 2);
                    PKTAP(aB01, ky + 0, kx + 3);
                    PKTAP(aB10, ky + 1, kx + 2);
                    PKTAP(aB11, ky + 1, kx + 3);
                }
            }
        }
        float mA0 = fmaxf(fmaxf(aA00[0], aA01[0]), fmaxf(aA10[0], aA11[0]));
        float mA1 = fmaxf(fmaxf(aA00[1], aA01[1]), fmaxf(aA10[1], aA11[1]));
        float mB0 = fmaxf(fmaxf(aB00[0], aB01[0]), fmaxf(aB10[0], aB11[0]));
        float mB1 = fmaxf(fmaxf(aB00[1], aB01[1]), fmaxf(aB10[1], aB11[1]));
        int sA0 = (mA0 > 0.f) ? 1 : ((mA0 < 0.f) ? -1 : 0);
        int sA1 = (mA1 > 0.f) ? 1 : ((mA1 < 0.f) ? -1 : 0);
        int sB0 = (mB0 > 0.f) ? 1 : ((mB0 < 0.f) ? -1 : 0);
        int sB1 = (mB1 > 0.f) ? 1 : ((mB1 < 0.f) ? -1 : 0);
        dwA |= (uint32_t)(sA0 & 0xff) << (8 * (2 * lop));
        dwA |= (uint32_t)(sA1 & 0xff) << (8 * (2 * lop + 1));
        dwB |= (uint32_t)(sB0 & 0xff) << (8 * (2 * lop));
        dwB |= (uint32_t)(sB1 & 0xff) << (8 * (2 * lop + 1));
    }
#undef PKTAP

    // group g writes plane g (oc 4g..4g+3 bytes within that plane's dword)
    size_t base = (((size_t)ln * 2 + g) * 256 + oy) * 256 + 2 * tx;
    uint2 v; v.x = dwA; v.y = dwB;
    *(uint2*)(a1 + base) = v;
}

// ---- layer 2: conv(8->16), quad-tap MFMA (3 MFMAs/row-tile) --------------
// A2 out pixel-major [(y*254+x)*4 + ocg] (R23/R25, verified).
__global__ __launch_bounds__(256) void kconv2(const uint32_t* __restrict__ ain,
                                              const int* __restrict__ wm,
                                              uint32_t* __restrict__ aout) {
    __shared__ uint32_t stb[10][36][2];    // [row][x][icg], ICG=2
    int w    = threadIdx.x >> 6;
    int lane = threadIdx.x & 63;
    int x0 = blockIdx.x * 32;
    int y0 = blockIdx.y * 8;
    int ln = blockIdx.z;
    int xl = lane & 31;
    int h  = lane >> 5;

    const int4v* wmv = (const int4v*)wm;
    int4v bq[3];
#pragma unroll
    for (int q = 0; q < 3; ++q) bq[q] = wmv[q * 64 + lane];

    int ky0_[3], kx0_[3], ky1_[3], kx1_[3];
#pragma unroll
    for (int q = 0; q < 3; ++q) {
        int t0 = 4 * q + 2 * h; if (t0 > 8) t0 = 8;
        int t1 = 4 * q + 2 * h + 1; if (t1 > 8) t1 = 8;
        ky0_[q] = t0 / 3; kx0_[q] = t0 % 3;
        ky1_[q] = t1 / 3; kx1_[q] = t1 % 3;
    }

    const uint32_t* abase = ain + (size_t)ln * 2 * 256 * 256;
    for (int idx = threadIdx.x; idx < 10 * 36 * 2; idx += 256) {
        int icg = idx & 1;
        int r2 = idx >> 1;
        int xx = r2 % 36, row = r2 / 36;
        int gy = y0 + row, gx = x0 + xx;
        uint32_t val = 0;
        if (xx < 34 && gx < 256 && gy < 256)
            val = abase[((size_t)icg * 256 + gy) * 256 + gx];
        stb[row][xx][icg] = val;
    }
    __syncthreads();

    uint32_t* obase = aout + (size_t)ln * 254 * 254 * 4;

#pragma unroll
    for (int ry = 0; ry < 2; ++ry) {
        int yy = y0 + 2 * w + ry;
        int rb = 2 * w + ry;
        int16v acc = {};
#pragma unroll
        for (int q = 0; q < 3; ++q) {
            uint2 lo = *(const uint2*)&stb[rb + ky0_[q]][xl + kx0_[q]][0];
            uint2 hi = *(const uint2*)&stb[rb + ky1_[q]][xl + kx1_[q]][0];
            int4v bv; bv[0] = (int)lo.x; bv[1] = (int)lo.y;
            bv[2] = (int)hi.x; bv[3] = (int)hi.y;
            acc = __builtin_amdgcn_mfma_i32_32x32x32_i8(bq[q], bv, acc, 0, 0, 0);
        }
        bool ok = (yy < 254) && (x0 + xl < 254);
#pragma unroll
        for (int g = 0; g < 2; ++g) {
            int ocg = 2 * g + h;
            if (ok) {
                uint32_t dw = 0;
#pragma unroll
                for (int j = 0; j < 4; ++j) {
                    int v = min(max(acc[4 * g + j], -1), 1);
                    dw |= (uint32_t)(v & 0xff) << (8 * j);
                }
                obase[((size_t)yy * 254 + x0 + xl) * 4 + ocg] = dw;
            }
        }
    }
}

// ---- layers 3+4 fused, all-MFMA; phase 1 pair-tap (5 MFMAs/tile) ---------
__global__ __launch_bounds__(256) void kconv34(const uint32_t* __restrict__ a2,
                                               const int* __restrict__ w3m,
                                               const int* __restrict__ w4m,
                                               float* __restrict__ out, int n0) {
    __shared__ uint32_t sA2[12][68][4];      // rows y0..y0+11, cols x0..x0+65
    __shared__ uint32_t sA3[10 * 66 * 9];    // [row][px(66)][icg-dword(9 pad)]
    int w    = threadIdx.x >> 6;
    int lane = threadIdx.x & 63;
    int xl = lane & 31;
    int h  = lane >> 5;
    int x0 = blockIdx.x * 62;
    int y0 = blockIdx.y * 8;
    int ln = blockIdx.z;

    const int4v* wmv3 = (const int4v*)w3m;
    int4v bp[5];
#pragma unroll
    for (int p = 0; p < 5; ++p) bp[p] = wmv3[p * 64 + lane];

    int kyP[5], kxP[5];
#pragma unroll
    for (int p = 0; p < 5; ++p) {
        int t = (p < 4) ? (2 * p + h) : 8;
        kyP[p] = t / 3; kxP[p] = t % 3;
    }

    const uint32_t* abase = a2 + (size_t)ln * 254 * 254 * 4;
    for (int idx = threadIdx.x; idx < 12 * 64 * 4; idx += 256) {
        int row = idx >> 8;
        int xx  = (idx >> 2) & 63;
        int icg = idx & 3;
        int gy = y0 + row, gx = x0 + xx;
        uint32_t val = 0;
        if (gy < 254 && gx < 254)
            val = abase[((size_t)gy * 254 + gx) * 4 + icg];
        sA2[row][xx][icg] = val;
    }
    if (threadIdx.x < 96) {
        int row = threadIdx.x >> 3;
        int xx  = 64 + ((threadIdx.x >> 2) & 1);
        int icg = threadIdx.x & 3;
        int gy = y0 + row, gx = x0 + xx;
        uint32_t val = 0;
        if (gy < 254 && gx < 254)
            val = abase[((size_t)gy * 254 + gx) * 4 + icg];
        sA2[row][xx][icg] = val;
    }
    __syncthreads();

#pragma unroll
    for (int t5 = 0; t5 < 5; ++t5) {
        int t = t5 * 4 + w;
        int row = t >> 1, ct = t & 1;
        int16v acc = {};
#pragma unroll
        for (int p = 0; p < 5; ++p) {
            int4v a = *(const int4v*)&sA2[row + kyP[p]][ct * 32 + xl + kxP[p]][0];
            acc = __builtin_amdgcn_mfma_i32_32x32x32_i8(bp[p], a, acc, 0, 0, 0);
        }
        int pbase = (row * 66 + ct * 32 + xl) * 9;
#pragma unroll
        for (int g = 0; g < 4; ++g) {
            uint32_t dw = 0;
#pragma unroll
            for (int j = 0; j < 4; ++j) {
                int v = min(max(acc[4 * g + j], -1), 1);
                dw |= (uint32_t)(v & 0xff) << (8 * j);
            }
            sA3[pbase + 2 * g + h] = dw;
        }
    }

    const int4v* wmv4 = (const int4v*)w4m;
    int4v bf4[9];
#pragma unroll
    for (int t = 0; t < 9; ++t) bf4[t] = wmv4[t * 64 + lane];
    __syncthreads();

    size_t gn = (size_t)(n0 + ln);
#pragma unroll
    for (int t4 = 0; t4 < 4; ++t4) {
        int t = t4 * 4 + w;
        int y = t >> 1, ct2 = t & 1;
        int gy = y0 + y;
        int16v acc = {};
#pragma unroll
        for (int ky = 0; ky < 3; ++ky) {
#pragma unroll
            for (int kx = 0; kx < 3; ++kx) {
                const uint32_t* pb = &sA3[((y + ky) * 66 + ct2 * 32 + xl + kx) * 9 + h * 4];
                int4v bv;
                bv[0] = (int)pb[0]; bv[1] = (int)pb[1];
                bv[2] = (int)pb[2]; bv[3] = (int)pb[3];
                acc = __builtin_amdgcn_mfma_i32_32x32x32_i8(bf4[ky * 3 + kx], bv, acc, 0, 0, 0);
            }
        }
        if (h == 0) {
            int lx = ct2 * 32 + xl;
            if (lx < 62 && x0 + lx < 250 && gy < 250) {
                float v0 = fminf(fmaxf((float)acc[0], -1.f), 1.f);
                float v1 = fminf(fmaxf((float)acc[1], -1.f), 1.f);
                out[((gn * 2 + 0) * 250 + gy) * 250 + x0 + lx] = v0;
                out[((gn * 2 + 1) * 250 + gy) * 250 + x0 + lx] = v1;
            }
        }
    }
}

extern "C" void kernel_launch(void* const* d_in, const int* in_sizes, int n_in,
                              void* d_out, int out_size, void* d_ws, size_t ws_size,
                              hipStream_t stream) {
    const float* x  = (const float*)d_in[0];
    const float* w1 = (const float*)d_in[1];
    const float* w2 = (const float*)d_in[2];
    const float* w3 = (const float*)d_in[3];
    const float* w4 = (const float*)d_in[4];
    char* ws = (char*)d_ws;

    int*   w2m = (int*)(ws + WOFF_W2M);
    int*   w3m = (int*)(ws + WOFF_W3M);
    int*   w4m = (int*)(ws + WOFF_W4M);
    f32x2* w1d = (f32x2*)(ws + WOFF_W1D);
    float* out = (float*)d_out;

    size_t per = (size_t)A1_PB + (size_t)A2_PB;   // A3 never materialized
    int NC = 32;
    while (NC > 1 && (size_t)WEIGHTS_BYTES + (size_t)NC * per > ws_size) NC >>= 1;

    uint32_t* A1 = (uint32_t*)(ws + WEIGHTS_BYTES);
    uint32_t* A2 = (uint32_t*)(ws + WEIGHTS_BYTES + (size_t)NC * A1_PB);

    kprep<<<dim3(3), 256, 0, stream>>>(w1, w2, w3, w4, w2m, w3m, w4m, w1d);
    for (int n0 = 0; n0 < 32; n0 += NC) {
        k1<<<dim3(1, 256, NC), 256, 0, stream>>>(x, w1d, A1, n0);
        kconv2<<<dim3(8, 32, NC), 256, 0, stream>>>(A1, w2m, A2);
        kconv34<<<dim3(5, 32, NC), 256, 0, stream>>>(A2, w3m, w4m, out, n0);
    }
}

// Round 28
// 124.850 us; speedup vs baseline: 1.2901x; 1.2901x over previous
//
#include <hip/hip_runtime.h>
#include <hip/hip_bf16.h>
#include <cstdint>

// ---------------------------------------------------------------------------
// Binarized CNN. Verified numerics (R5-R26 passed bit-exact):
//  - binarize(x) == sign(x) exactly; layers 2-4 are exact small-int math in
//    any order -> any packing / instruction choice is safe.
//  - conv1: each accumulator chain MUST sum in (ky,kx,ic)-ascending order
//    (Eigen/XLA-CPU im2col). Chains independent; fma == mul+add (w in +-1/0).
//    DO NOT reorder WITHIN a chain. Pad value 1.0.
//  - k2/kconv34: tap-packed MFMA K-axis (R25, verified).
//  - R28: REVERT to R26 exactly (best measured: 125.7us). R27's oc-split
//    doubled global traffic (L1 didn't absorb the duplicated window) and
//    regressed k1 61->106us. k1 is at its latency/issue floor given the
//    bit-exact f32 chain-order contract.
// ---------------------------------------------------------------------------

typedef __attribute__((ext_vector_type(2)))  float f32x2;
typedef __attribute__((ext_vector_type(4)))  int int4v;
typedef __attribute__((ext_vector_type(16))) int int16v;

#define WOFF_W2M 0          // int[3*64*4]  (L2 quad-tap table)
#define WOFF_W3M 10240      // int[5*64*4]  (L3 pair-tap table)
#define WOFF_W4M 20480      // int[9*64*4]  (L4 table, K=32 full)
#define WOFF_W1D 30720      // f32x2[4*32]
#define WEIGHTS_BYTES 32768

#define A1_PB (2*256*256*4)     // bytes per batch (packed u32, 4 ch/dword)
#define A2_PB (254*254*4*4)     // bytes per batch (pixel-major, 4 ocg dwords)

__device__ __forceinline__ int fsign(float w) {
    return (w > 0.f) ? 1 : ((w < 0.f) ? -1 : 0);
}

// acc.lo += w.lo * v.lo ; acc.hi += w.hi * v.lo   (broadcast LOW of src1)
__device__ __forceinline__ void pkfma_lo(f32x2& acc, f32x2 w, f32x2 v) {
    asm("v_pk_fma_f32 %0, %1, %2, %0 op_sel:[0,0,0] op_sel_hi:[1,0,1]"
        : "+v"(acc) : "s"(w), "v"(v));
}
// acc.lo += w.lo * v.hi ; acc.hi += w.hi * v.hi   (broadcast HIGH of src1)
__device__ __forceinline__ void pkfma_hi(f32x2& acc, f32x2 w, f32x2 v) {
    asm("v_pk_fma_f32 %0, %1, %2, %0 op_sel:[0,1,0] op_sel_hi:[1,1,1]"
        : "+v"(acc) : "s"(w), "v"(v));
}

// ---- weight prep: 3 blocks (one per table group) -------------------------
__global__ __launch_bounds__(256) void kprep(const float* __restrict__ w1,
                                             const float* __restrict__ w2,
                                             const float* __restrict__ w3,
                                             const float* __restrict__ w4,
                                             int* __restrict__ w2m,
                                             int* __restrict__ w3m,
                                             int* __restrict__ w4m,
                                             f32x2* __restrict__ w1d) {
    int tid = threadIdx.x;
    int b = blockIdx.x;
    if (b == 0) {
        // L2 quad-tap table (R25-verified)
        for (int idx = tid; idx < 3 * 64; idx += 256) {
            int q = idx / 64, l = idx % 64;
            int oc = l & 31, hl = l >> 5;
            int wd[4] = {0, 0, 0, 0};
            for (int u = 0; u < 2; ++u) {
                int tap = 4 * q + 2 * hl + u;
                if (tap > 8) continue;
                for (int i = 0; i < 8; ++i) {
                    int s = (oc < 16) ? fsign(w2[(oc * 8 + i) * 9 + tap]) : 0;
                    int j = 8 * u + i;
                    wd[j >> 2] |= (s & 0xff) << (8 * (j & 3));
                }
            }
            w2m[idx * 4 + 0] = wd[0]; w2m[idx * 4 + 1] = wd[1];
            w2m[idx * 4 + 2] = wd[2]; w2m[idx * 4 + 3] = wd[3];
        }
    } else if (b == 1) {
        // L3 pair-tap table (R25-verified)
        for (int idx = tid; idx < 5 * 64; idx += 256) {
            int p = idx / 64, l = idx % 64;
            int oc = l & 31, hl = l >> 5;
            int wd[4] = {0, 0, 0, 0};
            int tap = (p < 4) ? (2 * p + hl) : ((hl == 0) ? 8 : -1);
            if (tap >= 0) {
                for (int j = 0; j < 16; ++j) {
                    int s = fsign(w3[(oc * 16 + j) * 9 + tap]);
                    wd[j >> 2] |= (s & 0xff) << (8 * (j & 3));
                }
            }
            w3m[idx * 4 + 0] = wd[0]; w3m[idx * 4 + 1] = wd[1];
            w3m[idx * 4 + 2] = wd[2]; w3m[idx * 4 + 3] = wd[3];
        }
    } else {
        // L4 table: K=32 all real, only oc 0,1 nonzero (R22-verified)
        for (int idx = tid; idx < 576; idx += 256) {
            int t = idx / 64, l = idx % 64;
            int oc = l & 31, icb = (l >> 5) * 16;
            int wd[4] = {0, 0, 0, 0};
            for (int j = 0; j < 16; ++j) {
                int ic = icb + j;
                int s = (oc < 2) ? fsign(w4[(oc * 32 + ic) * 9 + t]) : 0;
                wd[j >> 2] |= (s & 0xff) << (8 * (j & 3));
            }
            w4m[idx * 4 + 0] = wd[0]; w4m[idx * 4 + 1] = wd[1];
            w4m[idx * 4 + 2] = wd[2]; w4m[idx * 4 + 3] = wd[3];
        }
        for (int i = tid; i < 128; i += 256) {
            int op = i / 32, t = i % 32;
            f32x2 pr = {0.f, 0.f};
            if (t < 27) {
                float wa = w1[(2 * op) * 27 + t];
                float wbv = w1[(2 * op + 1) * 27 + t];
                pr[0] = (wa > 0.f) ? 1.f : ((wa < 0.f) ? -1.f : 0.f);
                pr[1] = (wbv > 0.f) ? 1.f : ((wbv < 0.f) ? -1.f : 0.f);
            }
            w1d[i] = pr;
        }
    }
}

// ---- layer 1: pad(1)+conv(3->8)+hardtanh+maxpool2+sign, packed out -------
// R26 (verified, best): 256-thread blocks, 2 oy rows per block. Per-thread
// computation BIT-IDENTICAL to R20 (chains strict (ky,kx,ic)-ascending).
__global__ __launch_bounds__(256, 4) void k1(const float* __restrict__ x,
                                             const f32x2* __restrict__ w1d,
                                             uint32_t* __restrict__ a1, int n0) {
    int tx = threadIdx.x & 127;              // 0..127
    int oy = blockIdx.y * 2 + (threadIdx.x >> 7);   // 0..255
    int ln = blockIdx.z;
    const float* xn = x + (size_t)(n0 + ln) * 3 * 512 * 512;

    int iy0 = 2 * oy - 1;
    int xb  = 4 * tx;        // window cols xb-1 .. xb+4

    f32x2 P[3][4][3];        // [ic][r][pair]

    if (oy > 0 && oy < 255 && tx > 0 && tx < 127) {
#pragma unroll
        for (int ic = 0; ic < 3; ++ic) {
            const float* xc = xn + (size_t)ic * 512 * 512;
#pragma unroll
            for (int r = 0; r < 4; ++r) {
                const float* rp = xc + (size_t)(iy0 + r) * 512 + xb;
                float  lft = rp[-1];
                float4 m   = *(const float4*)rp;    // cols xb..xb+3, 16B aligned
                float  rgt = rp[4];
                P[ic][r][0] = (f32x2){lft, m.x};
                P[ic][r][1] = (f32x2){m.y, m.z};
                P[ic][r][2] = (f32x2){m.w, rgt};
            }
        }
    } else {
        for (int ic = 0; ic < 3; ++ic) {
            const float* xc = xn + (size_t)ic * 512 * 512;
#pragma unroll
            for (int r = 0; r < 4; ++r) {
                int iy = iy0 + r;
                bool yok = ((unsigned)iy < 512u);
                float t[6];
#pragma unroll
                for (int c = 0; c < 6; ++c) {
                    int ix = xb - 1 + c;
                    t[c] = (yok && ((unsigned)ix < 512u))
                               ? xc[(size_t)iy * 512 + ix] : 1.0f;
                }
                P[ic][r][0] = (f32x2){t[0], t[1]};
                P[ic][r][1] = (f32x2){t[2], t[3]};
                P[ic][r][2] = (f32x2){t[4], t[5]};
            }
        }
    }

#define PKTAP(ACC, ROW, COL)                                         \
    do {                                                             \
        if (((COL) & 1) == 0) pkfma_lo(ACC, ww, P[ic][ROW][(COL) >> 1]); \
        else                  pkfma_hi(ACC, ww, P[ic][ROW][(COL) >> 1]); \
    } while (0)

    uint64_t dallA = 0, dallB = 0;
#pragma unroll 1
    for (int op = 0; op < 4; ++op) {
        const f32x2* wb = w1d + op * 32;
        f32x2 wop[27];
#pragma unroll
        for (int t = 0; t < 27; ++t) wop[t] = wb[t];

        f32x2 aA00 = {0.f, 0.f}, aA01 = {0.f, 0.f};
        f32x2 aA10 = {0.f, 0.f}, aA11 = {0.f, 0.f};
        f32x2 aB00 = {0.f, 0.f}, aB01 = {0.f, 0.f};
        f32x2 aB10 = {0.f, 0.f}, aB11 = {0.f, 0.f};
#pragma unroll
        for (int ky = 0; ky < 3; ++ky) {
#pragma unroll
            for (int kx = 0; kx < 3; ++kx) {
#pragma unroll
                for (int ic = 0; ic < 3; ++ic) {
                    f32x2 ww = wop[ic * 9 + ky * 3 + kx];
                    PKTAP(aA00, ky + 0, kx + 0);
                    PKTAP(aA01, ky + 0, kx + 1);
                    PKTAP(aA10, ky + 1, kx + 0);
                    PKTAP(aA11, ky + 1, kx + 1);
                    PKTAP(aB00, ky + 0, kx + 2);
                    PKTAP(aB01, ky + 0, kx + 3);
                    PKTAP(aB10, ky + 1, kx + 2);
                    PKTAP(aB11, ky + 1, kx + 3);
                }
            }
        }
        float mA0 = fmaxf(fmaxf(aA00[0], aA01[0]), fmaxf(aA10[0], aA11[0]));
        float mA1 = fmaxf(fmaxf(aA00[1], aA01[1]), fmaxf(aA10[1], aA11[1]));
        float mB0 = fmaxf(fmaxf(aB00[0], aB01[0]), fmaxf(aB10[0], aB11[0]));
        float mB1 = fmaxf(fmaxf(aB00[1], aB01[1]), fmaxf(aB10[1], aB11[1]));
        int sA0 = (mA0 > 0.f) ? 1 : ((mA0 < 0.f) ? -1 : 0);
        int sA1 = (mA1 > 0.f) ? 1 : ((mA1 < 0.f) ? -1 : 0);
        int sB0 = (mB0 > 0.f) ? 1 : ((mB0 < 0.f) ? -1 : 0);
        int sB1 = (mB1 > 0.f) ? 1 : ((mB1 < 0.f) ? -1 : 0);
        dallA |= (uint64_t)(uint32_t)(sA0 & 0xff) << (8 * (2 * op));
        dallA |= (uint64_t)(uint32_t)(sA1 & 0xff) << (8 * (2 * op + 1));
        dallB |= (uint64_t)(uint32_t)(sB0 & 0xff) << (8 * (2 * op));
        dallB |= (uint64_t)(uint32_t)(sB1 & 0xff) << (8 * (2 * op + 1));
    }
#undef PKTAP

    size_t base = (((size_t)ln * 2) * 256 + oy) * 256 + 2 * tx;
    uint2 v0, v1;
    v0.x = (uint32_t)dallA;         v0.y = (uint32_t)dallB;
    v1.x = (uint32_t)(dallA >> 32); v1.y = (uint32_t)(dallB >> 32);
    *(uint2*)(a1 + base)             = v0;
    *(uint2*)(a1 + base + 256 * 256) = v1;
}

// ---- layer 2: conv(8->16), quad-tap MFMA (3 MFMAs/row-tile) --------------
// A2 out pixel-major [(y*254+x)*4 + ocg] (R23/R25, verified).
__global__ __launch_bounds__(256) void kconv2(const uint32_t* __restrict__ ain,
                                              const int* __restrict__ wm,
                                              uint32_t* __restrict__ aout) {
    __shared__ uint32_t stb[10][36][2];    // [row][x][icg], ICG=2
    int w    = threadIdx.x >> 6;
    int lane = threadIdx.x & 63;
    int x0 = blockIdx.x * 32;
    int y0 = blockIdx.y * 8;
    int ln = blockIdx.z;
    int xl = lane & 31;
    int h  = lane >> 5;

    const int4v* wmv = (const int4v*)wm;
    int4v bq[3];
#pragma unroll
    for (int q = 0; q < 3; ++q) bq[q] = wmv[q * 64 + lane];

    int ky0_[3], kx0_[3], ky1_[3], kx1_[3];
#pragma unroll
    for (int q = 0; q < 3; ++q) {
        int t0 = 4 * q + 2 * h; if (t0 > 8) t0 = 8;
        int t1 = 4 * q + 2 * h + 1; if (t1 > 8) t1 = 8;
        ky0_[q] = t0 / 3; kx0_[q] = t0 % 3;
        ky1_[q] = t1 / 3; kx1_[q] = t1 % 3;
    }

    const uint32_t* abase = ain + (size_t)ln * 2 * 256 * 256;
    for (int idx = threadIdx.x; idx < 10 * 36 * 2; idx += 256) {
        int icg = idx & 1;
        int r2 = idx >> 1;
        int xx = r2 % 36, row = r2 / 36;
        int gy = y0 + row, gx = x0 + xx;
        uint32_t val = 0;
        if (xx < 34 && gx < 256 && gy < 256)
            val = abase[((size_t)icg * 256 + gy) * 256 + gx];
        stb[row][xx][icg] = val;
    }
    __syncthreads();

    uint32_t* obase = aout + (size_t)ln * 254 * 254 * 4;

#pragma unroll
    for (int ry = 0; ry < 2; ++ry) {
        int yy = y0 + 2 * w + ry;
        int rb = 2 * w + ry;
        int16v acc = {};
#pragma unroll
        for (int q = 0; q < 3; ++q) {
            uint2 lo = *(const uint2*)&stb[rb + ky0_[q]][xl + kx0_[q]][0];
            uint2 hi = *(const uint2*)&stb[rb + ky1_[q]][xl + kx1_[q]][0];
            int4v bv; bv[0] = (int)lo.x; bv[1] = (int)lo.y;
            bv[2] = (int)hi.x; bv[3] = (int)hi.y;
            acc = __builtin_amdgcn_mfma_i32_32x32x32_i8(bq[q], bv, acc, 0, 0, 0);
        }
        bool ok = (yy < 254) && (x0 + xl < 254);
#pragma unroll
        for (int g = 0; g < 2; ++g) {
            int ocg = 2 * g + h;
            if (ok) {
                uint32_t dw = 0;
#pragma unroll
                for (int j = 0; j < 4; ++j) {
                    int v = min(max(acc[4 * g + j], -1), 1);
                    dw |= (uint32_t)(v & 0xff) << (8 * j);
                }
                obase[((size_t)yy * 254 + x0 + xl) * 4 + ocg] = dw;
            }
        }
    }
}

// ---- layers 3+4 fused, all-MFMA; phase 1 pair-tap (5 MFMAs/tile) ---------
__global__ __launch_bounds__(256) void kconv34(const uint32_t* __restrict__ a2,
                                               const int* __restrict__ w3m,
                                               const int* __restrict__ w4m,
                                               float* __restrict__ out, int n0) {
    __shared__ uint32_t sA2[12][68][4];      // rows y0..y0+11, cols x0..x0+65
    __shared__ uint32_t sA3[10 * 66 * 9];    // [row][px(66)][icg-dword(9 pad)]
    int w    = threadIdx.x >> 6;
    int lane = threadIdx.x & 63;
    int xl = lane & 31;
    int h  = lane >> 5;
    int x0 = blockIdx.x * 62;
    int y0 = blockIdx.y * 8;
    int ln = blockIdx.z;

    const int4v* wmv3 = (const int4v*)w3m;
    int4v bp[5];
#pragma unroll
    for (int p = 0; p < 5; ++p) bp[p] = wmv3[p * 64 + lane];

    int kyP[5], kxP[5];
#pragma unroll
    for (int p = 0; p < 5; ++p) {
        int t = (p < 4) ? (2 * p + h) : 8;
        kyP[p] = t / 3; kxP[p] = t % 3;
    }

    const uint32_t* abase = a2 + (size_t)ln * 254 * 254 * 4;
    for (int idx = threadIdx.x; idx < 12 * 64 * 4; idx += 256) {
        int row = idx >> 8;
        int xx  = (idx >> 2) & 63;
        int icg = idx & 3;
        int gy = y0 + row, gx = x0 + xx;
        uint32_t val = 0;
        if (gy < 254 && gx < 254)
            val = abase[((size_t)gy * 254 + gx) * 4 + icg];
        sA2[row][xx][icg] = val;
    }
    if (threadIdx.x < 96) {
        int row = threadIdx.x >> 3;
        int xx  = 64 + ((threadIdx.x >> 2) & 1);
        int icg = threadIdx.x & 3;
        int gy = y0 + row, gx = x0 + xx;
        uint32_t val = 0;
        if (gy < 254 && gx < 254)
            val = abase[((size_t)gy * 254 + gx) * 4 + icg];
        sA2[row][xx][icg] = val;
    }
    __syncthreads();

#pragma unroll
    for (int t5 = 0; t5 < 5; ++t5) {
        int t = t5 * 4 + w;
        int row = t >> 1, ct = t & 1;
        int16v acc = {};
#pragma unroll
        for (int p = 0; p < 5; ++p) {
            int4v a = *(const int4v*)&sA2[row + kyP[p]][ct * 32 + xl + kxP[p]][0];
            acc = __builtin_amdgcn_mfma_i32_32x32x32_i8(bp[p], a, acc, 0, 0, 0);
        }
        int pbase = (row * 66 + ct * 32 + xl) * 9;
#pragma unroll
        for (int g = 0; g < 4; ++g) {
            uint32_t dw = 0;
#pragma unroll
            for (int j = 0; j < 4; ++j) {
                int v = min(max(acc[4 * g + j], -1), 1);
                dw |= (uint32_t)(v & 0xff) << (8 * j);
            }
            sA3[pbase + 2 * g + h] = dw;
        }
    }

    const int4v* wmv4 = (const int4v*)w4m;
    int4v bf4[9];
#pragma unroll
    for (int t = 0; t < 9; ++t) bf4[t] = wmv4[t * 64 + lane];
    __syncthreads();

    size_t gn = (size_t)(n0 + ln);
#pragma unroll
    for (int t4 = 0; t4 < 4; ++t4) {
        int t = t4 * 4 + w;
        int y = t >> 1, ct2 = t & 1;
        int gy = y0 + y;
        int16v acc = {};
#pragma unroll
        for (int ky = 0; ky < 3; ++ky) {
#pragma unroll
            for (int kx = 0; kx < 3; ++kx) {
                const uint32_t* pb = &sA3[((y + ky) * 66 + ct2 * 32 + xl + kx) * 9 + h * 4];
                int4v bv;
                bv[0] = (int)pb[0]; bv[1] = (int)pb[1];
                bv[2] = (int)pb[2]; bv[3] = (int)pb[3];
                acc = __builtin_amdgcn_mfma_i32_32x32x32_i8(bf4[ky * 3 + kx], bv, acc, 0, 0, 0);
            }
        }
        if (h == 0) {
            int lx = ct2 * 32 + xl;
            if (lx < 62 && x0 + lx < 250 && gy < 250) {
                float v0 = fminf(fmaxf((float)acc[0], -1.f), 1.f);
                float v1 = fminf(fmaxf((float)acc[1], -1.f), 1.f);
                out[((gn * 2 + 0) * 250 + gy) * 250 + x0 + lx] = v0;
                out[((gn * 2 + 1) * 250 + gy) * 250 + x0 + lx] = v1;
            }
        }
    }
}

extern "C" void kernel_launch(void* const* d_in, const int* in_sizes, int n_in,
                              void* d_out, int out_size, void* d_ws, size_t ws_size,
                              hipStream_t stream) {
    const float* x  = (const float*)d_in[0];
    const float* w1 = (const float*)d_in[1];
    const float* w2 = (const float*)d_in[2];
    const float* w3 = (const float*)d_in[3];
    const float* w4 = (const float*)d_in[4];
    char* ws = (char*)d_ws;

    int*   w2m = (int*)(ws + WOFF_W2M);
    int*   w3m = (int*)(ws + WOFF_W3M);
    int*   w4m = (int*)(ws + WOFF_W4M);
    f32x2* w1d = (f32x2*)(ws + WOFF_W1D);
    float* out = (float*)d_out;

    size_t per = (size_t)A1_PB + (size_t)A2_PB;   // A3 never materialized
    int NC = 32;
    while (NC > 1 && (size_t)WEIGHTS_BYTES + (size_t)NC * per > ws_size) NC >>= 1;

    uint32_t* A1 = (uint32_t*)(ws + WEIGHTS_BYTES);
    uint32_t* A2 = (uint32_t*)(ws + WEIGHTS_BYTES + (size_t)NC * A1_PB);

    kprep<<<dim3(3), 256, 0, stream>>>(w1, w2, w3, w4, w2m, w3m, w4m, w1d);
    for (int n0 = 0; n0 < 32; n0 += NC) {
        k1<<<dim3(1, 128, NC), 256, 0, stream>>>(x, w1d, A1, n0);
        kconv2<<<dim3(8, 32, NC), 256, 0, stream>>>(A1, w2m, A2);
        kconv34<<<dim3(5, 32, NC), 256, 0, stream>>>(A2, w3m, w4m, out, n0);
    }
}